// Round 1
// baseline (379.151 us; speedup 1.0000x reference)
//
#include <hip/hip_runtime.h>
#include <hip/hip_bf16.h>

#define N_NODES 50000
#define N_EDGES 800000
#define DIM 256      // input feature dim
#define QKDIM 256    // packed q|k per node
// pre = (0.5/H) * sum_A (q_s k_d + q_d k_s) = total/16

__device__ __forceinline__ float bf2f(unsigned short u) {
    union { unsigned int i; float f; } v;
    v.i = ((unsigned int)u) << 16;
    return v.f;
}

// ---------------- Projection GEMM ----------------
// qk[n][j] = sum_d x[n][d] * W'[j][d] + b'[j]
// W' rows: j<128 -> Wq[j], else Wk[j-128]. Output bf16, packed [q|k].
__global__ __launch_bounds__(256) void proj_kernel(
    const float* __restrict__ x,
    const float* __restrict__ Wq, const float* __restrict__ bq,
    const float* __restrict__ Wk, const float* __restrict__ bk,
    __hip_bfloat16* __restrict__ qk)
{
    __shared__ float Xs[16][68];   // [k][m], pitch 68 keeps float4 alignment, shifts banks
    __shared__ float Ws[16][68];   // [k][n]

    const int by = blockIdx.y;                 // 0..3 -> 64-col slice of 256 outputs
    const int bm = blockIdx.x * 64;            // node base
    const float* Wbase = (by < 2) ? (Wq + (size_t)by * 64 * DIM)
                                  : (Wk + (size_t)(by - 2) * 64 * DIM);
    const float* bbase = (by < 2) ? (bq + by * 64) : (bk + (by - 2) * 64);

    const int tid = threadIdx.x;
    const int tx = tid & 15;        // col group (4 cols each)
    const int ty = tid >> 4;        // row group (4 rows each)
    const int lm = tid >> 2;        // staging: row 0..63
    const int lk = (tid & 3) * 4;   // staging: k chunk 0,4,8,12

    float acc[4][4] = {};

    for (int k0 = 0; k0 < DIM; k0 += 16) {
        // stage X tile [64 nodes x 16 k]
        int node = bm + lm;
        float4 xv = make_float4(0.f, 0.f, 0.f, 0.f);
        if (node < N_NODES)
            xv = *(const float4*)(x + (size_t)node * DIM + k0 + lk);
        Xs[lk + 0][lm] = xv.x; Xs[lk + 1][lm] = xv.y;
        Xs[lk + 2][lm] = xv.z; Xs[lk + 3][lm] = xv.w;
        // stage W tile [64 outputs x 16 k]
        float4 wv = *(const float4*)(Wbase + (size_t)lm * DIM + k0 + lk);
        Ws[lk + 0][lm] = wv.x; Ws[lk + 1][lm] = wv.y;
        Ws[lk + 2][lm] = wv.z; Ws[lk + 3][lm] = wv.w;
        __syncthreads();

        #pragma unroll
        for (int kk = 0; kk < 16; ++kk) {
            const float4 av = *(const float4*)&Xs[kk][ty * 4];
            const float4 bv = *(const float4*)&Ws[kk][tx * 4];
            const float a[4] = {av.x, av.y, av.z, av.w};
            const float b[4] = {bv.x, bv.y, bv.z, bv.w};
            #pragma unroll
            for (int i = 0; i < 4; ++i)
                #pragma unroll
                for (int j = 0; j < 4; ++j)
                    acc[i][j] += a[i] * b[j];
        }
        __syncthreads();
    }

    const int colbase = by * 64;
    #pragma unroll
    for (int i = 0; i < 4; ++i) {
        const int node = bm + ty * 4 + i;
        if (node >= N_NODES) break;
        #pragma unroll
        for (int j = 0; j < 4; ++j) {
            const int col = tx * 4 + j;
            const float v = acc[i][j] + bbase[col];
            qk[(size_t)node * QKDIM + colbase + col] = __float2bfloat16(v);
        }
    }
}

// ---------------- Edge scoring + scatter ----------------
// one wave per edge; lane i: s-row elems [4i,4i+4), d-row elems [(4i+128)&255 ...)
__global__ __launch_bounds__(256) void edge_kernel(
    const __hip_bfloat16* __restrict__ qk,
    const int* __restrict__ edge_index,   // [2][E]
    const int* __restrict__ d0,           // d0_index row 1, [2E]
    float* __restrict__ out)              // [0..N)=diagA0 (pre-zeroed), [N..N+E)=diagA1
{
    const int wave = (blockIdx.x * blockDim.x + threadIdx.x) >> 6;
    const int lane = threadIdx.x & 63;
    if (wave >= N_EDGES) return;
    const int e = wave;

    const int src = edge_index[e];
    const int dst = edge_index[N_EDGES + e];

    const unsigned short* rs = (const unsigned short*)qk + (size_t)src * QKDIM;
    const unsigned short* rd = (const unsigned short*)qk + (size_t)dst * QKDIM;

    const int so = lane * 4;
    const int dofs = (so + 128) & 255;

    const ushort4 a = *(const ushort4*)(rs + so);
    const ushort4 b = *(const ushort4*)(rd + dofs);

    float p = bf2f(a.x) * bf2f(b.x) + bf2f(a.y) * bf2f(b.y) +
              bf2f(a.z) * bf2f(b.z) + bf2f(a.w) * bf2f(b.w);

    #pragma unroll
    for (int off = 32; off > 0; off >>= 1)
        p += __shfl_xor(p, off, 64);

    const float val = __expf(p * 0.0625f);   // /16 = 0.5 * mean over 8 heads

    if (lane == 0) {
        out[N_NODES + e] = val;
        atomicAdd(&out[d0[2 * e]], val);
    } else if (lane == 1) {
        atomicAdd(&out[d0[2 * e + 1]], val);
    }
}

extern "C" void kernel_launch(void* const* d_in, const int* in_sizes, int n_in,
                              void* d_out, int out_size, void* d_ws, size_t ws_size,
                              hipStream_t stream) {
    const float* x  = (const float*)d_in[0];
    const float* Wq = (const float*)d_in[1];
    const float* bq = (const float*)d_in[2];
    const float* Wk = (const float*)d_in[3];
    const float* bk = (const float*)d_in[4];
    const int* edge_index = (const int*)d_in[5];
    const int* d0 = (const int*)d_in[6] + 2 * N_EDGES;  // row 1 of d0_index
    float* out = (float*)d_out;
    __hip_bfloat16* qk = (__hip_bfloat16*)d_ws;         // 50000*256*2 = 25.6 MB

    // zero the diagA0 accumulation region (d_out is poisoned 0xAA each call)
    hipMemsetAsync(d_out, 0, N_NODES * sizeof(float), stream);

    dim3 g1((N_NODES + 63) / 64, 4);
    proj_kernel<<<g1, 256, 0, stream>>>(x, Wq, bq, Wk, bk, qk);

    const int waves_per_block = 4;                       // 256 threads
    const int nblocks = (N_EDGES + waves_per_block - 1) / waves_per_block;
    edge_kernel<<<nblocks, 256, 0, stream>>>(qk, edge_index, d0, out);
}

// Round 2
// 263.782 us; speedup vs baseline: 1.4374x; 1.4374x over previous
//
#include <hip/hip_runtime.h>
#include <hip/hip_bf16.h>

#define N_NODES 50000
#define N_EDGES 800000
#define DIM 256      // input feature dim = K
#define QKDIM 256    // packed q|k per node
// pre = (0.5/H) * sum_A (q_s k_d + q_d k_s) = (full rotated 256-dot)/16

typedef __bf16 bfrag  __attribute__((ext_vector_type(8)));
typedef __bf16 bf4    __attribute__((ext_vector_type(4)));
typedef float  ffrag  __attribute__((ext_vector_type(4)));

__device__ __forceinline__ float bf2f(unsigned short u) {
    union { unsigned int i; float f; } v;
    v.i = ((unsigned int)u) << 16;
    return v.f;
}

// ---------------- W' fp32 -> bf16 (once per call, tiny) ----------------
// Wb[c][d], c<128 -> Wq[c][d], else Wk[c-128][d]. Flat: both halves contiguous.
__global__ __launch_bounds__(256) void cvt_w(
    const float* __restrict__ Wq, const float* __restrict__ Wk,
    __bf16* __restrict__ Wb)
{
    const int i = (blockIdx.x * 256 + threadIdx.x) * 4;   // grid 64 -> 65536 elems
    const float* s = (i < 32768) ? (Wq + i) : (Wk + (i - 32768));
    const float4 v = *(const float4*)s;
    bf4 o;
    o[0] = (__bf16)v.x; o[1] = (__bf16)v.y; o[2] = (__bf16)v.z; o[3] = (__bf16)v.w;
    *(bf4*)(Wb + i) = o;
}

// ---------------- Projection via MFMA bf16 ----------------
// qk[n][j] = sum_d x[n][d] * W'[j][d] + b'[j], stored bf16 packed [q|k].
// Block: 64 nodes x 256 cols. Wave w: 64 nodes x cols [64w, 64w+64).
__global__ __launch_bounds__(256) void proj_mfma(
    const float* __restrict__ x,
    const __bf16* __restrict__ Wb,
    const float* __restrict__ bq, const float* __restrict__ bk,
    __bf16* __restrict__ qk)
{
    const int tid  = threadIdx.x;
    const int wv   = tid >> 6;         // 0..3 -> 64-col slice
    const int lane = tid & 63;
    const int m    = lane & 15;        // A row / B col / C col
    const int q    = lane >> 4;        // quad
    const int mbase = blockIdx.x * 64;

    ffrag acc[4][4] = {};              // [m-tile][n-tile]

    #pragma unroll
    for (int s = 0; s < 8; ++s) {      // K-steps of 32
        const int kb = 32 * s + 8 * q; // A[m][kb..kb+8) per lane
        bfrag a[4];
        #pragma unroll
        for (int mt = 0; mt < 4; ++mt) {
            int row = mbase + mt * 16 + m;
            row = row < N_NODES ? row : N_NODES - 1;   // clamp, store guarded later
            const float* xp = x + (size_t)row * DIM + kb;
            const float4 lo = *(const float4*)xp;
            const float4 hi = *(const float4*)(xp + 4);
            bfrag t;
            t[0] = (__bf16)lo.x; t[1] = (__bf16)lo.y;
            t[2] = (__bf16)lo.z; t[3] = (__bf16)lo.w;
            t[4] = (__bf16)hi.x; t[5] = (__bf16)hi.y;
            t[6] = (__bf16)hi.z; t[7] = (__bf16)hi.w;
            a[mt] = t;
        }
        bfrag b[4];
        #pragma unroll
        for (int nt = 0; nt < 4; ++nt) {
            const int col = wv * 64 + nt * 16 + m;     // B[kb..kb+8)[col]
            b[nt] = *(const bfrag*)(Wb + (size_t)col * DIM + kb);
        }
        #pragma unroll
        for (int mt = 0; mt < 4; ++mt)
            #pragma unroll
            for (int nt = 0; nt < 4; ++nt)
                acc[mt][nt] = __builtin_amdgcn_mfma_f32_16x16x32_bf16(
                                  a[mt], b[nt], acc[mt][nt], 0, 0, 0);
    }

    // Epilogue: C layout col=lane&15, row=quad*4+reg
    #pragma unroll
    for (int nt = 0; nt < 4; ++nt) {
        const int col  = wv * 64 + nt * 16 + m;
        const float bias = (col < 128) ? bq[col] : bk[col - 128];
        #pragma unroll
        for (int mt = 0; mt < 4; ++mt) {
            #pragma unroll
            for (int r = 0; r < 4; ++r) {
                const int row = mbase + mt * 16 + q * 4 + r;
                if (row < N_NODES)
                    qk[(size_t)row * QKDIM + col] = (__bf16)(acc[mt][nt][r] + bias);
            }
        }
    }
}

// ---------------- Edge scoring + scatter ----------------
// 8 lanes per edge, 8 edges per wave. Lane j of edge-group g:
//   src bytes [128i+16j, +16) for i=0..3  (elements 64i+8j..+7)
//   dst bytes 128*((i+2)&3)+16j           (the (t+128)&255 rotation)
__global__ __launch_bounds__(256) void edge_kernel(
    const __bf16* __restrict__ qk,
    const int* __restrict__ edge_index,   // [2][E]
    const int* __restrict__ d0,           // d0_index row 1, [2E]
    float* __restrict__ out)              // [0..N)=diagA0 (pre-zeroed), [N..N+E)=diagA1
{
    const int wave = (blockIdx.x * blockDim.x + threadIdx.x) >> 6;
    const int lane = threadIdx.x & 63;
    const int g = lane >> 3;              // edge within wave
    const int j = lane & 7;               // lane within edge
    const int e = wave * 8 + g;
    if (e >= N_EDGES) return;

    const int src = edge_index[e];
    const int dst = edge_index[N_EDGES + e];

    const char* rs = (const char*)qk + (size_t)src * (QKDIM * 2);
    const char* rd = (const char*)qk + (size_t)dst * (QKDIM * 2);

    float4 a[4], b[4];
    #pragma unroll
    for (int i = 0; i < 4; ++i) {
        a[i] = *(const float4*)(rs + 128 * i + 16 * j);
        b[i] = *(const float4*)(rd + 128 * ((i + 2) & 3) + 16 * j);
    }

    float p = 0.f;
    #pragma unroll
    for (int i = 0; i < 4; ++i) {
        const unsigned short* ua = (const unsigned short*)&a[i];
        const unsigned short* ub = (const unsigned short*)&b[i];
        #pragma unroll
        for (int t = 0; t < 8; ++t)
            p += bf2f(ua[t]) * bf2f(ub[t]);
    }

    // reduce across the 8 lanes of this edge group
    p += __shfl_xor(p, 1, 64);
    p += __shfl_xor(p, 2, 64);
    p += __shfl_xor(p, 4, 64);

    if (j < 2) {
        const float val = __expf(p * 0.0625f);   // /16 = 0.5 * mean over 8 heads
        const int target = d0[2 * e + j];
        if (j == 0) out[N_NODES + e] = val;      // diagA1, coalesced across groups
        atomicAdd(&out[target], val);
    }
}

extern "C" void kernel_launch(void* const* d_in, const int* in_sizes, int n_in,
                              void* d_out, int out_size, void* d_ws, size_t ws_size,
                              hipStream_t stream) {
    const float* x  = (const float*)d_in[0];
    const float* Wq = (const float*)d_in[1];
    const float* bq = (const float*)d_in[2];
    const float* Wk = (const float*)d_in[3];
    const float* bk = (const float*)d_in[4];
    const int* edge_index = (const int*)d_in[5];
    const int* d0 = (const int*)d_in[6] + 2 * N_EDGES;  // row 1 of d0_index
    float* out = (float*)d_out;

    __bf16* qk = (__bf16*)d_ws;                              // 25.6 MB
    __bf16* Wb = (__bf16*)((char*)d_ws + (size_t)N_NODES * QKDIM * 2);  // +128 KB

    // zero the diagA0 accumulation region (d_out poisoned 0xAA each call)
    hipMemsetAsync(d_out, 0, N_NODES * sizeof(float), stream);

    cvt_w<<<64, 256, 0, stream>>>(Wq, Wk, Wb);
    proj_mfma<<<(N_NODES + 63) / 64, 256, 0, stream>>>(x, Wb, bq, bk, qk);

    // 8 edges/wave, 4 waves/block -> 32 edges/block
    edge_kernel<<<(N_EDGES + 31) / 32, 256, 0, stream>>>(qk, edge_index, d0, out);
}

// Round 3
// 245.185 us; speedup vs baseline: 1.5464x; 1.0759x over previous
//
#include <hip/hip_runtime.h>
#include <hip/hip_bf16.h>

#define N_NODES 50000
#define N_EDGES 800000
#define DIM 256      // input feature dim = K
#define QKDIM 256    // packed q|k per node
// pre = (0.5/H) * sum_A (q_s k_d + q_d k_s) = (full rotated 256-dot)/16

typedef __bf16 bfrag  __attribute__((ext_vector_type(8)));
typedef __bf16 bf4    __attribute__((ext_vector_type(4)));
typedef float  ffrag  __attribute__((ext_vector_type(4)));

__device__ __forceinline__ float bf2f(unsigned short u) {
    union { unsigned int i; float f; } v;
    v.i = ((unsigned int)u) << 16;
    return v.f;
}

// ---------------- prep: W' fp32->bf16 + zero diagA0 region ----------------
// Wb[c][d], c<128 -> Wq[c][d], else Wk[c-128][d]. Grid 64 x 256.
__global__ __launch_bounds__(256) void prep_kernel(
    const float* __restrict__ Wq, const float* __restrict__ Wk,
    __bf16* __restrict__ Wb, float* __restrict__ out)
{
    const int tid = blockIdx.x * 256 + threadIdx.x;   // 0..16383
    const int i = tid * 4;                            // 65536 elems total
    const float* s = (i < 32768) ? (Wq + i) : (Wk + (i - 32768));
    const float4 v = *(const float4*)s;
    bf4 o;
    o[0] = (__bf16)v.x; o[1] = (__bf16)v.y; o[2] = (__bf16)v.z; o[3] = (__bf16)v.w;
    *(bf4*)(Wb + i) = o;

    // zero out[0..N_NODES) (poisoned 0xAA each call); 16384 threads * 4 floats
    if (i + 4 <= N_NODES) {
        *(float4*)(out + i) = make_float4(0.f, 0.f, 0.f, 0.f);
    } else if (i < N_NODES) {
        for (int t = i; t < N_NODES; ++t) out[t] = 0.f;
    }
}

// ---------------- Projection via MFMA bf16, LDS-staged A ----------------
// qk[n][j] = sum_d x[n][d] * W'[j][d] + b'[j], stored bf16 packed [q|k].
// Block: 64 nodes x 256 cols, 4 waves; wave w covers cols [64w, 64w+64).
// A-tile staged once in LDS in MFMA-fragment order:
//   element (row,k): seg = (k>>5)*4 + (row>>4); lane = ((k>>3)&3)*16 + (row&15)
//   LDS elem offset = seg*512 + lane*8 + (k&7)   -> ds_read_b128 = frag, conflict-free
__global__ __launch_bounds__(256) void proj_mfma(
    const float* __restrict__ x,
    const __bf16* __restrict__ Wb,
    const float* __restrict__ bq, const float* __restrict__ bk,
    __bf16* __restrict__ qk)
{
    __shared__ __bf16 As[64 * 256];   // 32 KB, fragment-order

    const int tid  = threadIdx.x;
    const int wv   = tid >> 6;         // 0..3 -> 64-col slice
    const int lane = tid & 63;
    const int m    = lane & 15;
    const int q    = lane >> 4;
    const int mbase = blockIdx.x * 64;

    // ---- stage A (64 rows x 256 k fp32 -> bf16 frags) ----
    {
        const int srow = tid >> 2;           // 0..63
        const int c4   = tid & 3;
        int grow = mbase + srow;
        grow = grow < N_NODES ? grow : N_NODES - 1;
        const float* xp = x + (size_t)grow * DIM;
        const int mt_ = srow >> 4, m_ = srow & 15;
        #pragma unroll
        for (int i = 0; i < 16; ++i) {
            const int k = c4 * 4 + 16 * i;
            const float4 v = *(const float4*)(xp + k);
            bf4 o;
            o[0] = (__bf16)v.x; o[1] = (__bf16)v.y;
            o[2] = (__bf16)v.z; o[3] = (__bf16)v.w;
            const int seg = (k >> 5) * 4 + mt_;
            const int ln  = ((k >> 3) & 3) * 16 + m_;
            *(bf4*)(As + seg * 512 + ln * 8 + (k & 7)) = o;
        }
    }
    __syncthreads();

    ffrag acc[4][4] = {};              // [m-tile][n-tile]

    #pragma unroll 2
    for (int s = 0; s < 8; ++s) {
        bfrag a[4], b[4];
        #pragma unroll
        for (int mt = 0; mt < 4; ++mt)
            a[mt] = *(const bfrag*)(As + (s * 4 + mt) * 512 + lane * 8);
        #pragma unroll
        for (int nt = 0; nt < 4; ++nt) {
            const int col = wv * 64 + nt * 16 + m;
            b[nt] = *(const bfrag*)(Wb + (size_t)col * DIM + 32 * s + 8 * q);
        }
        #pragma unroll
        for (int mt = 0; mt < 4; ++mt)
            #pragma unroll
            for (int nt = 0; nt < 4; ++nt)
                acc[mt][nt] = __builtin_amdgcn_mfma_f32_16x16x32_bf16(
                                  a[mt], b[nt], acc[mt][nt], 0, 0, 0);
    }

    // Epilogue: C layout col=lane&15, row=quad*4+reg
    #pragma unroll
    for (int nt = 0; nt < 4; ++nt) {
        const int col  = wv * 64 + nt * 16 + m;
        const float bias = (col < 128) ? bq[col] : bk[col - 128];
        #pragma unroll
        for (int mt = 0; mt < 4; ++mt) {
            #pragma unroll
            for (int r = 0; r < 4; ++r) {
                const int row = mbase + mt * 16 + q * 4 + r;
                if (row < N_NODES)
                    qk[(size_t)row * QKDIM + col] = (__bf16)(acc[mt][nt][r] + bias);
            }
        }
    }
}

// ---------------- Edge scoring + scatter ----------------
// 8 lanes per edge, 8 edges per wave. Lane j of edge-group g:
//   src bytes [128i+16j, +16) for i=0..3  (elements 64i+8j..+7)
//   dst bytes 128*((i+2)&3)+16j           (the (t+128)&255 rotation)
__global__ __launch_bounds__(256) void edge_kernel(
    const __bf16* __restrict__ qk,
    const int* __restrict__ edge_index,   // [2][E]
    const int* __restrict__ d0,           // d0_index row 1, [2E]
    float* __restrict__ out)              // [0..N)=diagA0 (pre-zeroed), [N..N+E)=diagA1
{
    const int wave = (blockIdx.x * blockDim.x + threadIdx.x) >> 6;
    const int lane = threadIdx.x & 63;
    const int g = lane >> 3;              // edge within wave
    const int j = lane & 7;               // lane within edge
    const int e = wave * 8 + g;
    if (e >= N_EDGES) return;

    const int src = edge_index[e];
    const int dst = edge_index[N_EDGES + e];

    const char* rs = (const char*)qk + (size_t)src * (QKDIM * 2);
    const char* rd = (const char*)qk + (size_t)dst * (QKDIM * 2);

    float4 a[4], b[4];
    #pragma unroll
    for (int i = 0; i < 4; ++i) {
        a[i] = *(const float4*)(rs + 128 * i + 16 * j);
        b[i] = *(const float4*)(rd + 128 * ((i + 2) & 3) + 16 * j);
    }

    float p = 0.f;
    #pragma unroll
    for (int i = 0; i < 4; ++i) {
        const unsigned short* ua = (const unsigned short*)&a[i];
        const unsigned short* ub = (const unsigned short*)&b[i];
        #pragma unroll
        for (int t = 0; t < 8; ++t)
            p += bf2f(ua[t]) * bf2f(ub[t]);
    }

    // reduce across the 8 lanes of this edge group
    p += __shfl_xor(p, 1, 64);
    p += __shfl_xor(p, 2, 64);
    p += __shfl_xor(p, 4, 64);

    if (j < 2) {
        const float val = __expf(p * 0.0625f);   // /16 = 0.5 * mean over 8 heads
        const int target = d0[2 * e + j];
        if (j == 0) out[N_NODES + e] = val;      // diagA1, coalesced across groups
        atomicAdd(&out[target], val);
    }
}

extern "C" void kernel_launch(void* const* d_in, const int* in_sizes, int n_in,
                              void* d_out, int out_size, void* d_ws, size_t ws_size,
                              hipStream_t stream) {
    const float* x  = (const float*)d_in[0];
    const float* Wq = (const float*)d_in[1];
    const float* bq = (const float*)d_in[2];
    const float* Wk = (const float*)d_in[3];
    const float* bk = (const float*)d_in[4];
    const int* edge_index = (const int*)d_in[5];
    const int* d0 = (const int*)d_in[6] + 2 * N_EDGES;  // row 1 of d0_index
    float* out = (float*)d_out;

    __bf16* qk = (__bf16*)d_ws;                              // 25.6 MB
    __bf16* Wb = (__bf16*)((char*)d_ws + (size_t)N_NODES * QKDIM * 2);  // +128 KB

    prep_kernel<<<64, 256, 0, stream>>>(Wq, Wk, Wb, out);
    proj_mfma<<<(N_NODES + 63) / 64, 256, 0, stream>>>(x, Wb, bq, bk, qk);

    // 8 edges/wave, 4 waves/block -> 32 edges/block
    edge_kernel<<<(N_EDGES + 31) / 32, 256, 0, stream>>>(qk, edge_index, d0, out);
}

// Round 4
// 229.597 us; speedup vs baseline: 1.6514x; 1.0679x over previous
//
#include <hip/hip_runtime.h>
#include <hip/hip_bf16.h>

#define N_NODES 50000
#define N_EDGES 800000
#define DIM 256      // input feature dim = K
#define QKDIM 256    // packed q|k per node (fp8: 256 B/row)
// pre = (0.5/H) * sum_A (q_s k_d + q_d k_s) = (full rotated 256-dot)/16

typedef __bf16 bfrag  __attribute__((ext_vector_type(8)));
typedef __bf16 bf4    __attribute__((ext_vector_type(4)));
typedef float  ffrag  __attribute__((ext_vector_type(4)));
typedef float  f2     __attribute__((ext_vector_type(2)));

// ---------------- prep: W' fp32->bf16 + zero diagA0 region ----------------
__global__ __launch_bounds__(256) void prep_kernel(
    const float* __restrict__ Wq, const float* __restrict__ Wk,
    __bf16* __restrict__ Wb, float* __restrict__ out)
{
    const int tid = blockIdx.x * 256 + threadIdx.x;   // 0..16383
    const int i = tid * 4;                            // 65536 elems total
    const float* s = (i < 32768) ? (Wq + i) : (Wk + (i - 32768));
    const float4 v = *(const float4*)s;
    bf4 o;
    o[0] = (__bf16)v.x; o[1] = (__bf16)v.y; o[2] = (__bf16)v.z; o[3] = (__bf16)v.w;
    *(bf4*)(Wb + i) = o;

    if (i + 4 <= N_NODES) {
        *(float4*)(out + i) = make_float4(0.f, 0.f, 0.f, 0.f);
    } else if (i < N_NODES) {
        for (int t = i; t < N_NODES; ++t) out[t] = 0.f;
    }
}

// ---------------- Projection via MFMA bf16, LDS-staged A, fp8 output ------
// qk8[n][j] = fp8(sum_d x[n][d] * W'[j][d] + b'[j]), packed [q|k].
__global__ __launch_bounds__(256) void proj_mfma(
    const float* __restrict__ x,
    const __bf16* __restrict__ Wb,
    const float* __restrict__ bq, const float* __restrict__ bk,
    unsigned char* __restrict__ qk8)
{
    __shared__ __bf16 As[64 * 256];   // 32 KB, fragment-order

    const int tid  = threadIdx.x;
    const int wv   = tid >> 6;         // 0..3 -> 64-col slice
    const int lane = tid & 63;
    const int m    = lane & 15;
    const int q    = lane >> 4;
    const int mbase = blockIdx.x * 64;

    // ---- stage A (64 rows x 256 k fp32 -> bf16 frags) ----
    {
        const int srow = tid >> 2;           // 0..63
        const int c4   = tid & 3;
        int grow = mbase + srow;
        grow = grow < N_NODES ? grow : N_NODES - 1;
        const float* xp = x + (size_t)grow * DIM;
        const int mt_ = srow >> 4, m_ = srow & 15;
        #pragma unroll
        for (int i = 0; i < 16; ++i) {
            const int k = c4 * 4 + 16 * i;
            const float4 v = *(const float4*)(xp + k);
            bf4 o;
            o[0] = (__bf16)v.x; o[1] = (__bf16)v.y;
            o[2] = (__bf16)v.z; o[3] = (__bf16)v.w;
            const int seg = (k >> 5) * 4 + mt_;
            const int ln  = ((k >> 3) & 3) * 16 + m_;
            *(bf4*)(As + seg * 512 + ln * 8 + (k & 7)) = o;
        }
    }
    __syncthreads();

    ffrag acc[4][4] = {};              // [m-tile][n-tile]

    #pragma unroll 2
    for (int s = 0; s < 8; ++s) {
        bfrag a[4], b[4];
        #pragma unroll
        for (int mt = 0; mt < 4; ++mt)
            a[mt] = *(const bfrag*)(As + (s * 4 + mt) * 512 + lane * 8);
        #pragma unroll
        for (int nt = 0; nt < 4; ++nt) {
            const int col = wv * 64 + nt * 16 + m;
            b[nt] = *(const bfrag*)(Wb + (size_t)col * DIM + 32 * s + 8 * q);
        }
        #pragma unroll
        for (int mt = 0; mt < 4; ++mt)
            #pragma unroll
            for (int nt = 0; nt < 4; ++nt)
                acc[mt][nt] = __builtin_amdgcn_mfma_f32_16x16x32_bf16(
                                  a[mt], b[nt], acc[mt][nt], 0, 0, 0);
    }

    // Epilogue: C layout col=lane&15, row=quad*4+reg; encode fp8 e4m3 bytes
    #pragma unroll
    for (int nt = 0; nt < 4; ++nt) {
        const int col  = wv * 64 + nt * 16 + m;
        const float bias = (col < 128) ? bq[col] : bk[col - 128];
        #pragma unroll
        for (int mt = 0; mt < 4; ++mt) {
            #pragma unroll
            for (int r = 0; r < 4; ++r) {
                const int row = mbase + mt * 16 + q * 4 + r;
                if (row < N_NODES) {
                    const float v = acc[mt][nt][r] + bias;
                    const int pk = __builtin_amdgcn_cvt_pk_fp8_f32(v, v, 0, false);
                    qk8[(size_t)row * QKDIM + col] = (unsigned char)(pk & 0xFF);
                }
            }
        }
    }
}

// ---------------- Edge scoring + scatter (fp8 gather) ----------------
// 4 lanes per edge, 16 edges per wave. Lane j covers elements [64j, 64j+64):
//   src bytes [64j, +64); dst bytes 64*((j+2)&3) (the (t+128)&255 rotation)
__global__ __launch_bounds__(256) void edge_kernel(
    const unsigned char* __restrict__ qk8,
    const int* __restrict__ edge_index,   // [2][E]
    const int* __restrict__ d0,           // d0_index row 1, [2E]
    float* __restrict__ out)              // [0..N)=diagA0 (pre-zeroed), [N..N+E)=diagA1
{
    const int wave = (blockIdx.x * blockDim.x + threadIdx.x) >> 6;
    const int lane = threadIdx.x & 63;
    const int g = lane >> 2;              // edge within wave (0..15)
    const int j = lane & 3;               // lane within edge
    const int e = wave * 16 + g;          // 800000 = 50000*16, no tail

    const int src = edge_index[e];
    const int dst = edge_index[N_EDGES + e];

    const uint4* rs = (const uint4*)(qk8 + (size_t)src * QKDIM + 64 * j);
    const uint4* rd = (const uint4*)(qk8 + (size_t)dst * QKDIM + 64 * ((j + 2) & 3));

    uint4 a[4], b[4];
    #pragma unroll
    for (int i = 0; i < 4; ++i) { a[i] = rs[i]; b[i] = rd[i]; }

    float p = 0.f;
    #pragma unroll
    for (int i = 0; i < 4; ++i) {
        const unsigned int* ua = (const unsigned int*)&a[i];
        const unsigned int* ub = (const unsigned int*)&b[i];
        #pragma unroll
        for (int t = 0; t < 4; ++t) {
            const f2 x0 = __builtin_amdgcn_cvt_pk_f32_fp8(ua[t], false);
            const f2 y0 = __builtin_amdgcn_cvt_pk_f32_fp8(ub[t], false);
            const f2 x1 = __builtin_amdgcn_cvt_pk_f32_fp8(ua[t], true);
            const f2 y1 = __builtin_amdgcn_cvt_pk_f32_fp8(ub[t], true);
            p += x0[0] * y0[0] + x0[1] * y0[1] + x1[0] * y1[0] + x1[1] * y1[1];
        }
    }

    // reduce across the 4 lanes of this edge group
    p += __shfl_xor(p, 1, 64);
    p += __shfl_xor(p, 2, 64);

    if (j < 2) {
        const float val = __expf(p * 0.0625f);   // /16 = 0.5 * mean over 8 heads
        const int target = d0[2 * e + j];
        if (j == 0) out[N_NODES + e] = val;      // diagA1
        atomicAdd(&out[target], val);
    }
}

extern "C" void kernel_launch(void* const* d_in, const int* in_sizes, int n_in,
                              void* d_out, int out_size, void* d_ws, size_t ws_size,
                              hipStream_t stream) {
    const float* x  = (const float*)d_in[0];
    const float* Wq = (const float*)d_in[1];
    const float* bq = (const float*)d_in[2];
    const float* Wk = (const float*)d_in[3];
    const float* bk = (const float*)d_in[4];
    const int* edge_index = (const int*)d_in[5];
    const int* d0 = (const int*)d_in[6] + 2 * N_EDGES;  // row 1 of d0_index
    float* out = (float*)d_out;

    unsigned char* qk8 = (unsigned char*)d_ws;                       // 12.8 MB
    __bf16* Wb = (__bf16*)((char*)d_ws + (size_t)N_NODES * QKDIM);   // +128 KB

    prep_kernel<<<64, 256, 0, stream>>>(Wq, Wk, Wb, out);
    proj_mfma<<<(N_NODES + 63) / 64, 256, 0, stream>>>(x, Wb, bq, bk, qk8);

    // 16 edges/wave, 4 waves/block -> 64 edges/block
    edge_kernel<<<N_EDGES / 64, 256, 0, stream>>>(qk8, edge_index, d0, out);
}

// Round 6
// 214.883 us; speedup vs baseline: 1.7645x; 1.0685x over previous
//
#include <hip/hip_runtime.h>
#include <hip/hip_bf16.h>

#define N_NODES 50000
#define N_EDGES 800000
#define DIM 256      // input feature dim = K
#define QKDIM 256    // packed q|k per node (fp8: 256 B/row)
// pre = (0.5/H) * sum_A (q_s k_d + q_d k_s) = (full rotated 256-dot)/16

typedef __bf16 bfrag  __attribute__((ext_vector_type(8)));
typedef __bf16 bf4    __attribute__((ext_vector_type(4)));
typedef float  ffrag  __attribute__((ext_vector_type(4)));
typedef float  f2     __attribute__((ext_vector_type(2)));

#define EP_PITCH 272   // epilogue LDS byte pitch (256+16)

// ---------------- prep: W' fp32->bf16 + zero diagA0 region ----------------
__global__ __launch_bounds__(256) void prep_kernel(
    const float* __restrict__ Wq, const float* __restrict__ Wk,
    __bf16* __restrict__ Wb, float* __restrict__ out)
{
    const int tid = blockIdx.x * 256 + threadIdx.x;   // 0..16383
    const int i = tid * 4;                            // 65536 elems total
    const float* s = (i < 32768) ? (Wq + i) : (Wk + (i - 32768));
    const float4 v = *(const float4*)s;
    bf4 o;
    o[0] = (__bf16)v.x; o[1] = (__bf16)v.y; o[2] = (__bf16)v.z; o[3] = (__bf16)v.w;
    *(bf4*)(Wb + i) = o;

    if (i + 4 <= N_NODES)   // 50000 % 4 == 0, covers exactly
        *(float4*)(out + i) = make_float4(0.f, 0.f, 0.f, 0.f);
}

// ---------------- Projection via MFMA bf16 ----------------
// Block: 64 nodes x 256 cols, 4 waves; wave wv covers cols [64wv, 64wv+64).
// A staged in LDS in fragment order; B preloaded to regs per K-half;
// epilogue via LDS transpose -> coalesced dwordx4 stores.
__global__ __launch_bounds__(256) void proj_mfma(
    const float* __restrict__ x,
    const __bf16* __restrict__ Wb,
    const float* __restrict__ bq, const float* __restrict__ bk,
    unsigned char* __restrict__ qk8)
{
    __shared__ __bf16 As[64 * 256];   // 32 KB, fragment-order; reused by epilogue

    const int tid  = threadIdx.x;
    const int wv   = tid >> 6;         // 0..3 -> 64-col slice
    const int lane = tid & 63;
    const int m    = lane & 15;
    const int q    = lane >> 4;
    const int mbase = blockIdx.x * 64;

    // ---- stage A (64 rows x 256 k fp32 -> bf16 frags) ----
    {
        const int srow = tid >> 2;           // 0..63
        const int c4   = tid & 3;
        int grow = mbase + srow;
        grow = grow < N_NODES ? grow : N_NODES - 1;
        const float* xp = x + (size_t)grow * DIM;
        const int mt_ = srow >> 4, m_ = srow & 15;
        #pragma unroll
        for (int i = 0; i < 16; ++i) {
            const int k = c4 * 4 + 16 * i;
            const float4 v = *(const float4*)(xp + k);
            bf4 o;
            o[0] = (__bf16)v.x; o[1] = (__bf16)v.y;
            o[2] = (__bf16)v.z; o[3] = (__bf16)v.w;
            const int seg = (k >> 5) * 4 + mt_;
            const int ln  = ((k >> 3) & 3) * 16 + m_;
            *(bf4*)(As + seg * 512 + ln * 8 + (k & 7)) = o;
        }
    }
    __syncthreads();

    ffrag acc[4][4] = {};              // [m-tile][n-tile]

    #pragma unroll
    for (int h = 0; h < 2; ++h) {
        // preload this K-half's B fragments (16 dwordx4, L2-hit, independent)
        bfrag b[4][4];                 // [k-step][n-tile]
        #pragma unroll
        for (int sp = 0; sp < 4; ++sp)
            #pragma unroll
            for (int nt = 0; nt < 4; ++nt) {
                const int col = wv * 64 + nt * 16 + m;
                b[sp][nt] = *(const bfrag*)(Wb + (size_t)col * DIM
                                            + 32 * (4 * h + sp) + 8 * q);
            }
        #pragma unroll
        for (int sp = 0; sp < 4; ++sp) {
            bfrag a[4];
            #pragma unroll
            for (int mt = 0; mt < 4; ++mt)
                a[mt] = *(const bfrag*)(As + ((4 * h + sp) * 4 + mt) * 512 + lane * 8);
            #pragma unroll
            for (int mt = 0; mt < 4; ++mt)
                #pragma unroll
                for (int nt = 0; nt < 4; ++nt)
                    acc[mt][nt] = __builtin_amdgcn_mfma_f32_16x16x32_bf16(
                                      a[mt], b[sp][nt], acc[mt][nt], 0, 0, 0);
        }
    }

    // ---- epilogue: fp8-encode into LDS (transpose), then coalesced stores
    __syncthreads();                    // all waves done reading As
    unsigned char* ep = (unsigned char*)As;   // [64][EP_PITCH] bytes, 17 KB
    #pragma unroll
    for (int nt = 0; nt < 4; ++nt) {
        const int col  = wv * 64 + nt * 16 + m;
        const float bias = (col < 128) ? bq[col] : bk[col - 128];
        #pragma unroll
        for (int mt = 0; mt < 4; ++mt) {
            #pragma unroll
            for (int r = 0; r < 4; ++r) {
                const int rl = mt * 16 + q * 4 + r;
                const float v = acc[mt][nt][r] + bias;
                const int pk = __builtin_amdgcn_cvt_pk_fp8_f32(v, v, 0, false);
                ep[rl * EP_PITCH + col] = (unsigned char)(pk & 0xFF);
            }
        }
    }
    __syncthreads();
    {
        const int rl = tid >> 2;              // 0..63
        const int ch = tid & 3;               // 64-B chunk
        const int grow = mbase + rl;
        if (grow < N_NODES) {
            const uint4* s4 = (const uint4*)(ep + rl * EP_PITCH + ch * 64);
            const uint4 t0 = s4[0], t1 = s4[1], t2 = s4[2], t3 = s4[3];
            uint4* g = (uint4*)(qk8 + (size_t)grow * QKDIM + ch * 64);
            g[0] = t0; g[1] = t1; g[2] = t2; g[3] = t3;
        }
    }
}

// ---------------- Edge scoring + scatter (fp8 gather) ----------------
// 4 lanes per edge, 16 edges per wave. Lane j covers src bytes [64j, +64);
// dst bytes 64*((j+2)&3) (the (t+128)&255 q|k rotation).  [R4 known-good]
__global__ __launch_bounds__(256) void edge_kernel(
    const unsigned char* __restrict__ qk8,
    const int* __restrict__ edge_index,   // [2][E]
    const int* __restrict__ d0,           // d0_index row 1, [2E]
    float* __restrict__ out)              // [0..N)=diagA0 (pre-zeroed), [N..N+E)=diagA1
{
    const int wave = (blockIdx.x * blockDim.x + threadIdx.x) >> 6;
    const int lane = threadIdx.x & 63;
    const int g = lane >> 2;              // edge within wave (0..15)
    const int j = lane & 3;               // lane within edge
    const int e = wave * 16 + g;          // 800000 = 50000*16, no tail

    const int src = edge_index[e];
    const int dst = edge_index[N_EDGES + e];

    const uint4* rs = (const uint4*)(qk8 + (size_t)src * QKDIM + 64 * j);
    const uint4* rd = (const uint4*)(qk8 + (size_t)dst * QKDIM + 64 * ((j + 2) & 3));

    uint4 a[4], b[4];
    #pragma unroll
    for (int i = 0; i < 4; ++i) { a[i] = rs[i]; b[i] = rd[i]; }

    float p = 0.f;
    #pragma unroll
    for (int i = 0; i < 4; ++i) {
        const unsigned int* ua = (const unsigned int*)&a[i];
        const unsigned int* ub = (const unsigned int*)&b[i];
        #pragma unroll
        for (int t = 0; t < 4; ++t) {
            const f2 x0 = __builtin_amdgcn_cvt_pk_f32_fp8(ua[t], false);
            const f2 y0 = __builtin_amdgcn_cvt_pk_f32_fp8(ub[t], false);
            const f2 x1 = __builtin_amdgcn_cvt_pk_f32_fp8(ua[t], true);
            const f2 y1 = __builtin_amdgcn_cvt_pk_f32_fp8(ub[t], true);
            p += x0[0] * y0[0] + x0[1] * y0[1] + x1[0] * y1[0] + x1[1] * y1[1];
        }
    }

    // reduce across the 4 lanes of this edge group
    p += __shfl_xor(p, 1, 64);
    p += __shfl_xor(p, 2, 64);

    if (j < 2) {
        const float val = __expf(p * 0.0625f);   // /16 = 0.5 * mean over 8 heads
        const int target = d0[2 * e + j];
        if (j == 0) out[N_NODES + e] = val;      // diagA1
        atomicAdd(&out[target], val);
    }
}

extern "C" void kernel_launch(void* const* d_in, const int* in_sizes, int n_in,
                              void* d_out, int out_size, void* d_ws, size_t ws_size,
                              hipStream_t stream) {
    const float* x  = (const float*)d_in[0];
    const float* Wq = (const float*)d_in[1];
    const float* bq = (const float*)d_in[2];
    const float* Wk = (const float*)d_in[3];
    const float* bk = (const float*)d_in[4];
    const int* edge_index = (const int*)d_in[5];
    const int* d0 = (const int*)d_in[6] + 2 * N_EDGES;  // row 1 of d0_index
    float* out = (float*)d_out;

    unsigned char* qk8 = (unsigned char*)d_ws;                       // 12.8 MB
    __bf16* Wb = (__bf16*)((char*)d_ws + (size_t)N_NODES * QKDIM);   // +128 KB

    prep_kernel<<<64, 256, 0, stream>>>(Wq, Wk, Wb, out);
    proj_mfma<<<(N_NODES + 63) / 64, 256, 0, stream>>>(x, Wb, bq, bk, qk8);

    // 16 edges/wave, 4 waves/block -> 64 edges/block
    edge_kernel<<<N_EDGES / 64, 256, 0, stream>>>(qk8, edge_index, d0, out);
}